// Round 2
// baseline (143.926 us; speedup 1.0000x reference)
//
#include <hip/hip_runtime.h>

// out[b,h,s,t] = ( (x*dm)[b,h,s,:] @ z[b,h,:,t] )
//   z = c0 + c1*u + c2*u^2 + c3*u^3,  u = y - 0.45
// Strip-persistent bf16 MFMA GEMM: each block = 128 rows x 1024 cols
// (8 col-tiles of 128), A staged once, B register-prefetched + LDS subtiled.

#define S_DIM 2048
#define D_DIM 64
#define LDA 72          // padded LDS stride (u16) for A tile [128][64]

typedef __attribute__((ext_vector_type(4))) float f32x4;
typedef __attribute__((ext_vector_type(8))) short bf16x8;

__device__ __forceinline__ unsigned short f2bf(float f) {
    unsigned int u = __float_as_uint(f);
    u = (u + 0x7FFFu + ((u >> 16) & 1u)) >> 16;   // RNE; inputs finite
    return (unsigned short)u;
}

__global__ __launch_bounds__(256, 3)
void poly_gemm_kernel(const float* __restrict__ x,
                      const float* __restrict__ y,
                      const float* __restrict__ dm,
                      float* __restrict__ out)
{
    __shared__ unsigned short As[128 * LDA];     // 18,432 B
    __shared__ unsigned short Bt[8 * 128 * 8];   // [k/8][n][8] subtiled, 16,384 B

    // ---- bijective chunked XCD swizzle (96 blocks/XCD -> 3 bh slices/XCD) ----
    const int b = blockIdx.x;
    int id2;
    if ((gridDim.x & 7) == 0) {
        const int chunk = gridDim.x >> 3;
        id2 = (b & 7) * chunk + (b >> 3);
    } else {
        id2 = b;
    }
    const int bh    = id2 >> 5;          // 32 blocks per (b,h)
    const int rr_   = id2 & 31;
    const int brow  = (rr_ >> 1) * 128;  // 16 row-strips
    const int halfc = (rr_ & 1) * 1024;  // 2 col-halves

    const int tid  = threadIdx.x;
    const int lane = tid & 63;
    const int wave = tid >> 6;
    const int wr = wave >> 1;            // 2x2 waves -> 64x64 sub-tiles
    const int wc = wave & 1;
    const int g  = lane >> 4;
    const int ln = lane & 15;

    // coef_i = sum_j C[idx+j] * 0.9^j (precomputed in double)
    const float c0 = 0.5213636139f;
    const float c1 = 13.612260634f;
    const float c2 = -2.620445619f;
    const float c3 = 46.05483778f;

    const int tcol = tid & 127;          // B staging: column within tile
    const int dblk = tid >> 7;           // 0..1
    const float* ybt = y + (size_t)bh * D_DIM * S_DIM + halfc + tcol;

    float breg[32];

    // ---- issue B loads for tile 0 (in flight during A staging) ----
    #pragma unroll
    for (int it = 0; it < 8; ++it) {
        #pragma unroll
        for (int q = 0; q < 4; ++q)
            breg[it * 4 + q] = ybt[(size_t)(it * 8 + dblk * 4 + q) * S_DIM];
    }

    // ---- stage A = bf16(x * dm) once per block ----
    const float* xb = x + ((size_t)bh * S_DIM + brow) * D_DIM;
    #pragma unroll
    for (int it = 0; it < 8; ++it) {
        int idx = tid + it * 256;        // 0..2047 float4s
        int r = idx >> 4;
        int c = (idx & 15) * 4;
        float s = dm[brow + r];
        f32x4 v = *(const f32x4*)(xb + r * D_DIM + c);
        ushort4 bv;
        bv.x = f2bf(v[0] * s); bv.y = f2bf(v[1] * s);
        bv.z = f2bf(v[2] * s); bv.w = f2bf(v[3] * s);
        *(ushort4*)&As[r * LDA + c] = bv;
    }

    __syncthreads();

    // ---- A fragments -> registers, kept for the whole block ----
    bf16x8 af[2][4];
    #pragma unroll
    for (int kk = 0; kk < 2; ++kk)
        #pragma unroll
        for (int mi = 0; mi < 4; ++mi)
            af[kk][mi] = *(const bf16x8*)&As[(wr * 64 + mi * 16 + ln) * LDA + kk * 32 + g * 8];

    // ---- convert B tile 0 -> bf16 subtiled LDS ----
    #pragma unroll
    for (int it = 0; it < 8; ++it) {
        ushort4 o;
        #pragma unroll
        for (int q = 0; q < 4; ++q) {
            float u = breg[it * 4 + q] - 0.45f;
            float z = c0 + u * (c1 + u * (c2 + u * c3));
            ((unsigned short*)&o)[q] = f2bf(z);
        }
        *(ushort4*)&Bt[(it * 128 + tcol) * 8 + dblk * 4] = o;
    }
    __syncthreads();

    // ---- main loop over 8 col-tiles ----
    for (int j = 0; j < 8; ++j) {
        // prefetch next tile's y into registers (overlaps MFMA + stores)
        if (j < 7) {
            const float* ybn = ybt + (j + 1) * 128;
            #pragma unroll
            for (int it = 0; it < 8; ++it) {
                #pragma unroll
                for (int q = 0; q < 4; ++q)
                    breg[it * 4 + q] = ybn[(size_t)(it * 8 + dblk * 4 + q) * S_DIM];
            }
        }

        // MFMA: 64x64 per wave, 4x4 fragments
        f32x4 acc[4][4] = {};
        #pragma unroll
        for (int kk = 0; kk < 2; ++kk) {
            bf16x8 bfr[4];
            #pragma unroll
            for (int ni = 0; ni < 4; ++ni) {
                int n = wc * 64 + ni * 16 + ln;
                bfr[ni] = *(const bf16x8*)&Bt[((kk * 4 + g) * 128 + n) * 8];
            }
            #pragma unroll
            for (int mi = 0; mi < 4; ++mi)
                #pragma unroll
                for (int ni = 0; ni < 4; ++ni)
                    acc[mi][ni] = __builtin_amdgcn_mfma_f32_16x16x32_bf16(
                        af[kk][mi], bfr[ni], acc[mi][ni], 0, 0, 0);
        }

        // store (dm already folded into A)
        const size_t orow = ((size_t)bh * S_DIM + brow + wr * 64) * S_DIM
                          + halfc + j * 128 + wc * 64 + ln;
        #pragma unroll
        for (int mi = 0; mi < 4; ++mi)
            #pragma unroll
            for (int r4 = 0; r4 < 4; ++r4) {
                size_t base = orow + (size_t)(mi * 16 + g * 4 + r4) * S_DIM;
                #pragma unroll
                for (int ni = 0; ni < 4; ++ni)
                    out[base + ni * 16] = acc[mi][ni][r4];
            }

        __syncthreads();   // all waves done reading Bt

        if (j < 7) {
            // convert prefetched regs -> Bt (compiler inserts vmcnt wait)
            #pragma unroll
            for (int it = 0; it < 8; ++it) {
                ushort4 o;
                #pragma unroll
                for (int q = 0; q < 4; ++q) {
                    float u = breg[it * 4 + q] - 0.45f;
                    float z = c0 + u * (c1 + u * (c2 + u * c3));
                    ((unsigned short*)&o)[q] = f2bf(z);
                }
                *(ushort4*)&Bt[(it * 128 + tcol) * 8 + dblk * 4] = o;
            }
        }
        __syncthreads();   // Bt ready for next iteration
    }
}

extern "C" void kernel_launch(void* const* d_in, const int* in_sizes, int n_in,
                              void* d_out, int out_size, void* d_ws, size_t ws_size,
                              hipStream_t stream) {
    const float* x  = (const float*)d_in[0];
    const float* y  = (const float*)d_in[1];
    const float* dm = (const float*)d_in[2];
    float* out = (float*)d_out;

    const int BH = in_sizes[0] / (S_DIM * D_DIM);   // 24
    dim3 grid(BH * 32);                              // 768 blocks = 3/CU, co-resident
    poly_gemm_kernel<<<grid, 256, 0, stream>>>(x, y, dm, out);
}

// Round 3
// 102.905 us; speedup vs baseline: 1.3986x; 1.3986x over previous
//
#include <hip/hip_runtime.h>

// out[b,h,s,t] = ( (x*dm)[b,h,s,:] @ z[b,h,:,t] )
//   z = c0 + c1*u + c2*u^2 + c3*u^3,  u = y - 0.45
// Independent 128x128 bf16-MFMA blocks (R1 structure) +
//   XCD-chunked swizzle, 4 blocks/CU, subtiled B, nt stores, dm folded into A.

#define S_DIM 2048
#define D_DIM 64
#define LDA 72          // padded LDS stride (u16) for A tile [128][64]

typedef __attribute__((ext_vector_type(4))) float f32x4;
typedef __attribute__((ext_vector_type(8))) short bf16x8;

__device__ __forceinline__ unsigned short f2bf(float f) {
    unsigned int u = __float_as_uint(f);
    u = (u + 0x7FFFu + ((u >> 16) & 1u)) >> 16;   // RNE; inputs finite
    return (unsigned short)u;
}

__global__ __launch_bounds__(256, 4)
void poly_gemm_kernel(const float* __restrict__ x,
                      const float* __restrict__ y,
                      const float* __restrict__ dm,
                      float* __restrict__ out)
{
    __shared__ unsigned short As[128 * LDA];     // 18,432 B
    __shared__ unsigned short Bt[8 * 128 * 8];   // [k/8][n][8] subtiled, 16,384 B

    // ---- bijective chunked XCD swizzle: XCD k owns id2 in [k*chunk,(k+1)*chunk)
    //      chunk = 768 = 3 (b,h) slices; x+y per slice = 1 MB -> fits 4 MB L2.
    const int b = blockIdx.x;
    int id2;
    if ((gridDim.x & 7) == 0) {
        const int chunk = gridDim.x >> 3;
        id2 = (b & 7) * chunk + (b >> 3);
    } else {
        id2 = b;
    }
    const int bh   = id2 >> 8;             // 256 blocks per (b,h)
    const int t    = id2 & 255;
    const int brow = (t >> 4) * 128;
    const int bcol = (t & 15) * 128;

    const int tid  = threadIdx.x;
    const int lane = tid & 63;
    const int wave = tid >> 6;
    const int wr = wave >> 1;              // 2x2 waves -> 64x64 sub-tiles
    const int wc = wave & 1;
    const int g  = lane >> 4;
    const int ln = lane & 15;

    // coef_i = sum_j C[idx+j] * 0.9^j (precomputed in double)
    const float c0 = 0.5213636139f;
    const float c1 = 13.612260634f;
    const float c2 = -2.620445619f;
    const float c3 = 46.05483778f;

    // ---- stage A = bf16(x * dm) ----
    const float* xb = x + ((size_t)bh * S_DIM + brow) * D_DIM;
    #pragma unroll
    for (int it = 0; it < 8; ++it) {
        int idx = tid + it * 256;          // 0..2047 float4s
        int r = idx >> 4;
        int c = (idx & 15) * 4;
        float s = dm[brow + r];
        f32x4 v = *(const f32x4*)(xb + r * D_DIM + c);
        ushort4 bv;
        bv.x = f2bf(v[0] * s); bv.y = f2bf(v[1] * s);
        bv.z = f2bf(v[2] * s); bv.w = f2bf(v[3] * s);
        *(ushort4*)&As[r * LDA + c] = bv;
    }

    // ---- stage B: z = poly(y - 0.45) -> subtiled LDS [k/8][n][8] ----
    // thread loads 4 k-rows (dblk half) at one column; 256 threads = 512B/row seg
    const int tcol = tid & 127;
    const int dblk = tid >> 7;
    const float* ybt = y + (size_t)bh * D_DIM * S_DIM + bcol + tcol;
    #pragma unroll
    for (int it = 0; it < 8; ++it) {
        ushort4 o;
        #pragma unroll
        for (int q = 0; q < 4; ++q) {
            float u = ybt[(size_t)(it * 8 + dblk * 4 + q) * S_DIM] - 0.45f;
            float z = c0 + u * (c1 + u * (c2 + u * c3));
            ((unsigned short*)&o)[q] = f2bf(z);
        }
        *(ushort4*)&Bt[(it * 128 + tcol) * 8 + dblk * 4] = o;
    }

    __syncthreads();

    // ---- MFMA: each wave 64x64 (4x4 fragments), K=64 in 2 steps ----
    f32x4 acc[4][4] = {};
    #pragma unroll
    for (int kk = 0; kk < 2; ++kk) {
        bf16x8 af[4];
        #pragma unroll
        for (int mi = 0; mi < 4; ++mi)
            af[mi] = *(const bf16x8*)&As[(wr * 64 + mi * 16 + ln) * LDA + kk * 32 + g * 8];
        bf16x8 bfr[4];
        #pragma unroll
        for (int ni = 0; ni < 4; ++ni) {
            int n = wc * 64 + ni * 16 + ln;
            bfr[ni] = *(const bf16x8*)&Bt[((kk * 4 + g) * 128 + n) * 8];
        }
        #pragma unroll
        for (int mi = 0; mi < 4; ++mi)
            #pragma unroll
            for (int ni = 0; ni < 4; ++ni)
                acc[mi][ni] = __builtin_amdgcn_mfma_f32_16x16x32_bf16(
                    af[mi], bfr[ni], acc[mi][ni], 0, 0, 0);
    }

    // ---- epilogue: nontemporal f32 stores (dm already folded into A) ----
    // C/D layout: col = lane&15, row = (lane>>4)*4 + reg
    const size_t orow = ((size_t)bh * S_DIM + brow + wr * 64) * S_DIM
                      + bcol + wc * 64 + ln;
    #pragma unroll
    for (int mi = 0; mi < 4; ++mi)
        #pragma unroll
        for (int r4 = 0; r4 < 4; ++r4) {
            size_t base = orow + (size_t)(mi * 16 + g * 4 + r4) * S_DIM;
            #pragma unroll
            for (int ni = 0; ni < 4; ++ni)
                __builtin_nontemporal_store(acc[mi][ni][r4], &out[base + ni * 16]);
        }
}

extern "C" void kernel_launch(void* const* d_in, const int* in_sizes, int n_in,
                              void* d_out, int out_size, void* d_ws, size_t ws_size,
                              hipStream_t stream) {
    const float* x  = (const float*)d_in[0];
    const float* y  = (const float*)d_in[1];
    const float* dm = (const float*)d_in[2];
    float* out = (float*)d_out;

    const int BH = in_sizes[0] / (S_DIM * D_DIM);   // 24
    dim3 grid(BH * 256);                             // 6144 blocks, 1D for swizzle
    poly_gemm_kernel<<<grid, 256, 0, stream>>>(x, y, dm, out);
}

// Round 4
// 73.531 us; speedup vs baseline: 1.9574x; 1.3995x over previous
//
#include <hip/hip_runtime.h>

// out[b,h,s,t] = ( (x*dm)[b,h,s,:] @ z[b,h,:,t] )
//   z = c0 + c1*u + c2*u^2 + c3*u^3,  u = y - 0.45
// Independent 128x128 bf16-MFMA blocks + XCD-chunked swizzle + subtiled B
// + LDS-transposed dwordx4 epilogue (stores: 64 dword -> 16 dwordx4 per lane).

#define S_DIM 2048
#define D_DIM 64
#define LDA 72          // padded LDS stride (u16) for A tile [128][64]

typedef __attribute__((ext_vector_type(4))) float f32x4;
typedef __attribute__((ext_vector_type(8))) short bf16x8;

__device__ __forceinline__ unsigned short f2bf(float f) {
    unsigned int u = __float_as_uint(f);
    u = (u + 0x7FFFu + ((u >> 16) & 1u)) >> 16;   // RNE; inputs finite
    return (unsigned short)u;
}

__global__ __launch_bounds__(256, 4)
void poly_gemm_kernel(const float* __restrict__ x,
                      const float* __restrict__ y,
                      const float* __restrict__ dm,
                      float* __restrict__ out)
{
    // 34,816 B shared: staging (As 18,432 + Bt 16,384) overlaid later by
    // per-wave 4 KB transpose buffers (16 KB total, reuses the As region).
    __shared__ __align__(16) char smem[18432 + 16384];
    unsigned short* As = (unsigned short*)smem;
    unsigned short* Bt = (unsigned short*)(smem + 18432);

    // ---- bijective chunked XCD swizzle: XCD k owns 3 consecutive (b,h) slices
    const int b = blockIdx.x;
    int id2;
    if ((gridDim.x & 7) == 0) {
        const int chunk = gridDim.x >> 3;
        id2 = (b & 7) * chunk + (b >> 3);
    } else {
        id2 = b;
    }
    const int bh   = id2 >> 8;             // 256 blocks per (b,h)
    const int t    = id2 & 255;
    const int brow = (t >> 4) * 128;
    const int bcol = (t & 15) * 128;

    const int tid  = threadIdx.x;
    const int lane = tid & 63;
    const int wave = tid >> 6;
    const int wr = wave >> 1;              // 2x2 waves -> 64x64 sub-tiles
    const int wc = wave & 1;
    const int g  = lane >> 4;
    const int ln = lane & 15;

    // coef_i = sum_j C[idx+j] * 0.9^j (precomputed in double)
    const float c0 = 0.5213636139f;
    const float c1 = 13.612260634f;
    const float c2 = -2.620445619f;
    const float c3 = 46.05483778f;

    // ---- stage A = bf16(x * dm) ----
    const float* xb = x + ((size_t)bh * S_DIM + brow) * D_DIM;
    #pragma unroll
    for (int it = 0; it < 8; ++it) {
        int idx = tid + it * 256;          // 0..2047 float4s
        int r = idx >> 4;
        int c = (idx & 15) * 4;
        float s = dm[brow + r];
        f32x4 v = *(const f32x4*)(xb + r * D_DIM + c);
        ushort4 bv;
        bv.x = f2bf(v[0] * s); bv.y = f2bf(v[1] * s);
        bv.z = f2bf(v[2] * s); bv.w = f2bf(v[3] * s);
        *(ushort4*)&As[r * LDA + c] = bv;
    }

    // ---- stage B: z = poly(y - 0.45) -> subtiled LDS [k/8][n][8] ----
    const int tcol = tid & 127;
    const int dblk = tid >> 7;
    const float* ybt = y + (size_t)bh * D_DIM * S_DIM + bcol + tcol;
    #pragma unroll
    for (int it = 0; it < 8; ++it) {
        ushort4 o;
        #pragma unroll
        for (int q = 0; q < 4; ++q) {
            float u = ybt[(size_t)(it * 8 + dblk * 4 + q) * S_DIM] - 0.45f;
            float z = c0 + u * (c1 + u * (c2 + u * c3));
            ((unsigned short*)&o)[q] = f2bf(z);
        }
        *(ushort4*)&Bt[(it * 128 + tcol) * 8 + dblk * 4] = o;
    }

    __syncthreads();

    // ---- MFMA: each wave 64x64 (4x4 fragments), K=64 in 2 steps ----
    f32x4 acc[4][4] = {};
    #pragma unroll
    for (int kk = 0; kk < 2; ++kk) {
        bf16x8 af[4];
        #pragma unroll
        for (int mi = 0; mi < 4; ++mi)
            af[mi] = *(const bf16x8*)&As[(wr * 64 + mi * 16 + ln) * LDA + kk * 32 + g * 8];
        bf16x8 bfr[4];
        #pragma unroll
        for (int ni = 0; ni < 4; ++ni) {
            int n = wc * 64 + ni * 16 + ln;
            bfr[ni] = *(const bf16x8*)&Bt[((kk * 4 + g) * 128 + n) * 8];
        }
        #pragma unroll
        for (int mi = 0; mi < 4; ++mi)
            #pragma unroll
            for (int ni = 0; ni < 4; ++ni)
                acc[mi][ni] = __builtin_amdgcn_mfma_f32_16x16x32_bf16(
                    af[mi], bfr[ni], acc[mi][ni], 0, 0, 0);
    }

    // ---- all waves done reading As/Bt -> safe to overlay transpose buffers
    __syncthreads();

    // per-wave [16][64] f32 buffer (4 KB each)
    float* Tw = (float*)smem + wave * 1024;

    // epilogue: transpose each 16x64 mi-group through LDS, store dwordx4 (nt)
    // acc layout: C_local[mi*16 + g*4 + r4][ni*16 + ln]
    const size_t orow0 = ((size_t)bh * S_DIM + brow + wr * 64) * S_DIM
                       + bcol + wc * 64;
    #pragma unroll
    for (int mi = 0; mi < 4; ++mi) {
        #pragma unroll
        for (int ni = 0; ni < 4; ++ni)
            #pragma unroll
            for (int r4 = 0; r4 < 4; ++r4)
                Tw[(g * 4 + r4) * 64 + ni * 16 + ln] = acc[mi][ni][r4];

        asm volatile("s_waitcnt lgkmcnt(0)" ::: "memory");
        __builtin_amdgcn_sched_barrier(0);

        f32x4 v[4];
        #pragma unroll
        for (int rr = 0; rr < 4; ++rr)
            v[rr] = *(const f32x4*)&Tw[(rr * 4 + g) * 64 + ln * 4];

        asm volatile("s_waitcnt lgkmcnt(0)" ::: "memory");
        __builtin_amdgcn_sched_barrier(0);

        #pragma unroll
        for (int rr = 0; rr < 4; ++rr) {
            size_t addr = orow0 + (size_t)(mi * 16 + rr * 4 + g) * S_DIM + ln * 4;
            __builtin_nontemporal_store(v[rr], (f32x4*)&out[addr]);
        }
    }
}

extern "C" void kernel_launch(void* const* d_in, const int* in_sizes, int n_in,
                              void* d_out, int out_size, void* d_ws, size_t ws_size,
                              hipStream_t stream) {
    const float* x  = (const float*)d_in[0];
    const float* y  = (const float*)d_in[1];
    const float* dm = (const float*)d_in[2];
    float* out = (float*)d_out;

    const int BH = in_sizes[0] / (S_DIM * D_DIM);   // 24
    dim3 grid(BH * 256);                             // 6144 blocks, 1D for swizzle
    poly_gemm_kernel<<<grid, 256, 0, stream>>>(x, y, dm, out);
}